// Round 1
// baseline (250.892 us; speedup 1.0000x reference)
//
#include <hip/hip_runtime.h>
#include <stdint.h>

#define IN_F   4096
#define OUT_F  4096
#define M_TOT  512
#define KT     (IN_F / 32)      // 128 global 32-wide k-steps
#define BN     64               // weight rows per block
#define BK     64               // K per staging iteration
#define KSPLIT 4
#define KPB    (IN_F / KSPLIT)  // 1024 K per block
#define NITER  (KPB / BK)       // 16 iterations

typedef unsigned short u16;
typedef __bf16 bf16x8 __attribute__((ext_vector_type(8)));
typedef float  f32x4  __attribute__((ext_vector_type(4)));
typedef int    i32x4  __attribute__((ext_vector_type(4)));
typedef float  fv4    __attribute__((ext_vector_type(4)));

__device__ __forceinline__ u16 f2bf(float x) {
    unsigned u = __float_as_uint(x);
    u += 0x7FFFu + ((u >> 16) & 1u);   // round-to-nearest-even
    return (u16)(u >> 16);
}

// ---- pass 0: input fp32 -> bf16, MFMA-A-fragment order in workspace ----
// Also zero-initializes the output (atomic-accumulated by qlinear; bias folded
// in by the kq==0 blocks). Fusing the zeroing here avoids a memset dispatch.
// aws[((mt*KT + kt)*64 + lane)*8 + j] = in[mt*16 + (lane&15)][kt*32 + (lane>>4)*8 + j]
__global__ void pack_a_kernel(const float* __restrict__ in, u16* __restrict__ aws,
                              float* __restrict__ outz) {
    int t    = blockIdx.x * blockDim.x + threadIdx.x;  // 262144 threads
    int lane = t & 63;
    int kt   = (t >> 6) & (KT - 1);
    int mt   = t >> 13;
    int m = mt * 16 + (lane & 15);
    int k = kt * 32 + ((lane >> 4) << 3);
    const float* src = in + (size_t)m * IN_F + k;
    float4 a0 = *(const float4*)src;
    float4 a1 = *(const float4*)(src + 4);
    union { u16 u[8]; uint4 v; } pk;
    pk.u[0]=f2bf(a0.x); pk.u[1]=f2bf(a0.y); pk.u[2]=f2bf(a0.z); pk.u[3]=f2bf(a0.w);
    pk.u[4]=f2bf(a1.x); pk.u[5]=f2bf(a1.y); pk.u[6]=f2bf(a1.z); pk.u[7]=f2bf(a1.w);
    *(uint4*)(aws + (size_t)t * 8) = pk.v;
    // zero out[512][4096]: 2M floats, 2x f32x4 per thread
    f32x4 z = {};
    ((f32x4*)outz)[t] = z;
    ((f32x4*)outz)[t + (M_TOT * OUT_F / 8)] = z;
}

// ---- main: fused dequant + GEMM; 256 blocks (64 n-tiles x 4 k-quarters), 1024 thr
// BM=512 (weights read exactly once), BN=64.
// R4 change 1: global loads issued at the TOP of the iteration, right after the
//   barrier — __syncthreads() drains vmcnt(0), so loads issued just before it
//   (old structure) serialized a full HBM round-trip per iteration. Issuing them
//   first lets the drain overlap the whole iteration body.
// R4 change 2: weight/outlier/grad loads are now CACHED (no nt) — the ~200 MB
//   input set fits in the 256 MiB L3, so steady-state reads can come from L3.
// R4 change 3: epilogue is fp32 atomicAdd directly into out (zeroed by pack_a,
//   bias folded in by kq==0). Eliminates the 32 MB partial store + reduce kernel.
__global__ __launch_bounds__(1024, 4) void qlinear_kernel(
    const u16*   __restrict__ aws,
    const int*   __restrict__ qw,
    const float* __restrict__ scales,
    const float* __restrict__ zeros,
    const float* __restrict__ outlier,
    const float* __restrict__ grad,
    const float* __restrict__ bias,
    float*       __restrict__ out)            // [512][4096], pre-zeroed
{
    // buffer = 8 frags (ks*4+nf) x 64 lanes x 8 bf16 = 8 KB; double-buffered 16 KB
    __shared__ __align__(16) u16 Bsh[2][8 * 64 * 8];

    const int tid  = threadIdx.x;
    const int lane = tid & 63;
    const int wv   = tid >> 6;                // 0..15, m-stripe [wv*32, +32)

    const int nblk = blockIdx.x >> 2;
    const int kq   = blockIdx.x & 3;
    const int n0   = nblk * BN;
    const int k0   = kq * KPB;

    // ---- staging role: thread covers weight row (n0+srow), 4-wide k-chunk ----
    const int srow = tid >> 4;                // 0..63
    const int schk = tid & 15;                // k_local = schk*4 (0..63)
    const int orow = n0 + srow;
    const float sr = scales[orow];
    const float c0 = -zeros[orow] * sr;       // w = q*s + (o*g - z*s)
    const size_t sg = (size_t)orow * IN_F + k0 + schk * 4;
    // B-frag coords (layout verified R1/R3): frag = ks*4+nf, lane = (n&15)|(quad<<4)
    const int sks   = schk >> 3;              // k_local>>5
    const int squad = (schk >> 1) & 3;        // (k_local>>3)&3
    const int j0    = (schk & 1) * 4;         // k_local&7 base
    const int snf   = srow >> 4;
    const int slane = (srow & 15) | (squad << 4);
    const int doff  = ((sks * 4 + snf) * 64 + slane) * 8 + j0;

    i32x4 qb[2]; fv4 ob[2], gb[2];
    auto ld = [&](int it) {
        int s = it & 1;
        size_t off = sg + (size_t)it * BK;
        qb[s] = *(const i32x4*)(qw      + off);   // cached: L3-resident inputs
        ob[s] = *(const fv4*)  (outlier + off);
        gb[s] = *(const fv4*)  (grad    + off);
    };
    auto st = [&](int it) {
        int s = it & 1;
        union { u16 u[4]; uint2 v; } pk;
        pk.u[0] = f2bf(fmaf((float)qb[s].x, sr, fmaf(ob[s].x, gb[s].x, c0)));
        pk.u[1] = f2bf(fmaf((float)qb[s].y, sr, fmaf(ob[s].y, gb[s].y, c0)));
        pk.u[2] = f2bf(fmaf((float)qb[s].z, sr, fmaf(ob[s].z, gb[s].z, c0)));
        pk.u[3] = f2bf(fmaf((float)qb[s].w, sr, fmaf(ob[s].w, gb[s].w, c0)));
        *(uint2*)(&Bsh[it & 1][doff]) = pk.v;
    };

    // A fragment base: frag (mf, d) at abase + (mf*KT + d)*512, d = global 32-k step
    const u16* abase = aws + ((size_t)(wv * 2) * KT + kq * (KPB / 32)) * 512
                           + (size_t)lane * 8;

    f32x4 acc[2][4] = {};

    ld(0);
    st(0);
    ld(1);
    __syncthreads();

    for (int it = 0; it < NITER; ++it) {
        // HBM loads FIRST — they age a full iteration before the barrier's
        // vmcnt(0) drain, instead of zero.
        if (it + 2 < NITER) ld(it + 2);

        // A loads next (L2/L3-resident, needed by the MFMAs below)
        bf16x8 af[2][2];
        #pragma unroll
        for (int ks = 0; ks < 2; ++ks)
            #pragma unroll
            for (int mf = 0; mf < 2; ++mf)
                af[ks][mf] = *(const bf16x8*)(abase + ((size_t)mf * KT + it * 2 + ks) * 512);

        // dequant+LDS-store for next iteration (its loads completed last iter;
        // counted vmcnt lets this pass without draining the fresh loads above)
        if (it + 1 < NITER) st(it + 1);

        const u16* bb = &Bsh[it & 1][0];
        #pragma unroll
        for (int ks = 0; ks < 2; ++ks) {
            bf16x8 bfr[4];
            #pragma unroll
            for (int nf = 0; nf < 4; ++nf)
                bfr[nf] = *(const bf16x8*)(bb + (((ks * 4 + nf) * 64) + lane) * 8);
            #pragma unroll
            for (int mf = 0; mf < 2; ++mf)
                #pragma unroll
                for (int nf = 0; nf < 4; ++nf)
                    acc[mf][nf] = __builtin_amdgcn_mfma_f32_16x16x32_bf16(
                        af[ks][mf], bfr[nf], acc[mf][nf], 0, 0, 0);
        }

        __syncthreads();
    }

    // ---- epilogue: fp32 atomic accumulate into out; kq==0 folds in bias ----
    const int cm0 = wv * 32 + ((lane >> 4) << 2);
    const int cn  = n0 + (lane & 15);
    float badd[4];
    #pragma unroll
    for (int nf = 0; nf < 4; ++nf)
        badd[nf] = (kq == 0) ? bias[cn + nf * 16] : 0.0f;
    #pragma unroll
    for (int mf = 0; mf < 2; ++mf)
        #pragma unroll
        for (int nf = 0; nf < 4; ++nf)
            #pragma unroll
            for (int r = 0; r < 4; ++r)
                unsafeAtomicAdd(out + (size_t)(cm0 + mf * 16 + r) * OUT_F + cn + nf * 16,
                                acc[mf][nf][r] + badd[nf]);
}

extern "C" void kernel_launch(void* const* d_in, const int* in_sizes, int n_in,
                              void* d_out, int out_size, void* d_ws, size_t ws_size,
                              hipStream_t stream) {
    const float* input   = (const float*)d_in[0];
    const int*   qweight = (const int*)  d_in[1];
    const float* scales  = (const float*)d_in[2];
    const float* zeros   = (const float*)d_in[3];
    const float* outlier = (const float*)d_in[4];
    const float* grad    = (const float*)d_in[5];
    const float* bias    = (const float*)d_in[6];
    float* out = (float*)d_out;

    u16* aws = (u16*)d_ws;                                  // 4 MB

    pack_a_kernel<<<(M_TOT * IN_F / 8) / 256, 256, 0, stream>>>(input, aws, out);
    qlinear_kernel<<<(OUT_F / BN) * KSPLIT, 1024, 0, stream>>>(
        aws, qweight, scales, zeros, outlier, grad, bias, out);
}

// Round 2
// 233.423 us; speedup vs baseline: 1.0748x; 1.0748x over previous
//
#include <hip/hip_runtime.h>
#include <stdint.h>

#define IN_F   4096
#define OUT_F  4096
#define M_TOT  512
#define KT     (IN_F / 32)      // 128 global 32-wide k-steps
#define BN     32               // weight rows per block (R5: 64->32 for 2 blocks/CU)
#define BK     128              // K per staging iteration (keeps LDS buffer 8 KB)
#define KSPLIT 4
#define KPB    (IN_F / KSPLIT)  // 1024 K per block
#define NITER  (KPB / BK)       // 8 iterations

typedef unsigned short u16;
typedef __bf16 bf16x8 __attribute__((ext_vector_type(8)));
typedef float  f32x4  __attribute__((ext_vector_type(4)));
typedef int    i32x4  __attribute__((ext_vector_type(4)));
typedef float  fv4    __attribute__((ext_vector_type(4)));

__device__ __forceinline__ u16 f2bf(float x) {
    unsigned u = __float_as_uint(x);
    u += 0x7FFFu + ((u >> 16) & 1u);   // round-to-nearest-even
    return (u16)(u >> 16);
}

// ---- pass 0: input fp32 -> bf16, MFMA-A-fragment order in workspace ----
// aws[((mt*KT + kt)*64 + lane)*8 + j] = in[mt*16 + (lane&15)][kt*32 + (lane>>4)*8 + j]
__global__ void pack_a_kernel(const float* __restrict__ in, u16* __restrict__ aws) {
    int t    = blockIdx.x * blockDim.x + threadIdx.x;  // 262144 threads
    int lane = t & 63;
    int kt   = (t >> 6) & (KT - 1);
    int mt   = t >> 13;
    int m = mt * 16 + (lane & 15);
    int k = kt * 32 + ((lane >> 4) << 3);
    const float* src = in + (size_t)m * IN_F + k;
    float4 a0 = *(const float4*)src;
    float4 a1 = *(const float4*)(src + 4);
    union { u16 u[8]; uint4 v; } pk;
    pk.u[0]=f2bf(a0.x); pk.u[1]=f2bf(a0.y); pk.u[2]=f2bf(a0.z); pk.u[3]=f2bf(a0.w);
    pk.u[4]=f2bf(a1.x); pk.u[5]=f2bf(a1.y); pk.u[6]=f2bf(a1.z); pk.u[7]=f2bf(a1.w);
    *(uint4*)(aws + (size_t)t * 8) = pk.v;
}

// ---- main: fused dequant + GEMM; 512 blocks (128 n-tiles x 4 k-quarters), 1024 thr
// BM=512 (weights read exactly once), BN=32.
// R5: 2 blocks/CU (512 blocks, 32 waves/CU) so one block's barrier vmcnt-drain is
//   covered by the co-resident block's compute+loads. R4's counters showed the
//   1-block/CU structure was latency-bound (Occ 40%, hbm 17%, MfmaUtil 6%).
// Register budget for 8 waves/EU (<=64 regs/wave): acc[2][2] (16 AGPR), 1-deep
//   staging prefetch (12 VGPR), per-ks A-frag loads. Epilogue: NT partial stores
//   (R4's atomic epilogue was a ~30 us serial tail of 8.4M word atomics).
__global__ __launch_bounds__(1024, 8) void qlinear_kernel(
    const u16*   __restrict__ aws,
    const int*   __restrict__ qw,
    const float* __restrict__ scales,
    const float* __restrict__ zeros,
    const float* __restrict__ outlier,
    const float* __restrict__ grad,
    float*       __restrict__ part)           // [KSPLIT][512][4096]
{
    // buffer = 8 frags (ks*2+nf) x 64 lanes x 8 bf16 = 8 KB; double-buffered 16 KB
    __shared__ __align__(16) u16 Bsh[2][8 * 64 * 8];

    const int tid  = threadIdx.x;
    const int lane = tid & 63;
    const int wv   = tid >> 6;                // 0..15, m-stripe [wv*32, +32)

    const int nblk = blockIdx.x >> 2;         // 0..127
    const int kq   = blockIdx.x & 3;
    const int n0   = nblk * BN;
    const int k0   = kq * KPB;

    // ---- staging role: thread covers weight row (n0+srow), 4-wide k-chunk ----
    const int srow = tid >> 5;                // 0..31
    const int schk = tid & 31;                // k_local = schk*4 (0..124)
    const int orow = n0 + srow;
    const float sr = scales[orow];
    const float c0 = -zeros[orow] * sr;       // w = q*s + (o*g - z*s)
    const size_t sg = (size_t)orow * IN_F + k0 + schk * 4;
    // B-frag coords: frag = ks*2+nf; lane = (n&15)|(quad<<4); elem j = k&7
    const int sks   = schk >> 3;              // k_local>>5   (0..3)
    const int squad = (schk >> 1) & 3;        // (k_local>>3)&3
    const int j0    = (schk & 1) * 4;         // k_local&7 base
    const int snf   = srow >> 4;              // 0..1
    const int slane = (srow & 15) | (squad << 4);
    const int doff  = ((sks * 2 + snf) * 64 + slane) * 8 + j0;

    i32x4 qb; fv4 ob, gb;
    auto ld = [&](int it) {
        size_t off = sg + (size_t)it * BK;
        qb = *(const i32x4*)(qw      + off);
        ob = *(const fv4*)  (outlier + off);
        gb = *(const fv4*)  (grad    + off);
    };
    auto st = [&](int it) {
        union { u16 u[4]; uint2 v; } pk;
        pk.u[0] = f2bf(fmaf((float)qb.x, sr, fmaf(ob.x, gb.x, c0)));
        pk.u[1] = f2bf(fmaf((float)qb.y, sr, fmaf(ob.y, gb.y, c0)));
        pk.u[2] = f2bf(fmaf((float)qb.z, sr, fmaf(ob.z, gb.z, c0)));
        pk.u[3] = f2bf(fmaf((float)qb.w, sr, fmaf(ob.w, gb.w, c0)));
        *(uint2*)(&Bsh[it & 1][doff]) = pk.v;
    };

    // A fragment base: frag (mf, d) at abase + (mf*KT + d)*512, d = global 32-k step
    const u16* abase = aws + ((size_t)(wv * 2) * KT + kq * (KPB / 32)) * 512
                           + (size_t)lane * 8;

    f32x4 acc[2][2] = {};

    ld(0);
    st(0);
    __syncthreads();

    for (int it = 0; it < NITER; ++it) {
        // next staging loads first: they age through the whole body before the
        // st() vmcnt-wait / bottom barrier
        if (it + 1 < NITER) ld(it + 1);

        const u16* bb = &Bsh[it & 1][0];
        const u16* ab = abase + (size_t)(it * 4) * 512;
        #pragma unroll
        for (int ks = 0; ks < 4; ++ks) {
            bf16x8 af0 = *(const bf16x8*)(ab + (size_t)ks * 512);
            bf16x8 af1 = *(const bf16x8*)(ab + ((size_t)KT + ks) * 512);
            bf16x8 bf0 = *(const bf16x8*)(bb + (((ks * 2 + 0) * 64) + lane) * 8);
            bf16x8 bf1 = *(const bf16x8*)(bb + (((ks * 2 + 1) * 64) + lane) * 8);
            acc[0][0] = __builtin_amdgcn_mfma_f32_16x16x32_bf16(af0, bf0, acc[0][0], 0, 0, 0);
            acc[0][1] = __builtin_amdgcn_mfma_f32_16x16x32_bf16(af0, bf1, acc[0][1], 0, 0, 0);
            acc[1][0] = __builtin_amdgcn_mfma_f32_16x16x32_bf16(af1, bf0, acc[1][0], 0, 0, 0);
            acc[1][1] = __builtin_amdgcn_mfma_f32_16x16x32_bf16(af1, bf1, acc[1][1], 0, 0, 0);
        }

        if (it + 1 < NITER) st(it + 1);   // waits on ld(it+1), aged a full body
        __syncthreads();
    }

    // ---- epilogue: fp32 partials, non-temporal (write-once-read-once) ----
    float* pout = part + (size_t)kq * (M_TOT * OUT_F);
    const int cm0 = wv * 32 + ((lane >> 4) << 2);
    const int cn  = n0 + (lane & 15);
    #pragma unroll
    for (int mf = 0; mf < 2; ++mf)
        #pragma unroll
        for (int nf = 0; nf < 2; ++nf)
            #pragma unroll
            for (int r = 0; r < 4; ++r)
                __builtin_nontemporal_store(
                    acc[mf][nf][r],
                    pout + (size_t)(cm0 + mf * 16 + r) * OUT_F + cn + nf * 16);
}

// ---- reduce: out = bias + sum_k partial[k] ----
__global__ void reduce_kernel(const fv4* __restrict__ part,
                              const fv4* __restrict__ bias,
                              fv4* __restrict__ out) {
    int idx = blockIdx.x * blockDim.x + threadIdx.x;   // 524288
    fv4 s = bias[idx & (OUT_F / 4 - 1)];
    const int STRIDE = M_TOT * OUT_F / 4;
    #pragma unroll
    for (int k = 0; k < KSPLIT; ++k) {
        fv4 p = __builtin_nontemporal_load(part + (size_t)k * STRIDE + idx);
        s += p;
    }
    out[idx] = s;
}

extern "C" void kernel_launch(void* const* d_in, const int* in_sizes, int n_in,
                              void* d_out, int out_size, void* d_ws, size_t ws_size,
                              hipStream_t stream) {
    const float* input   = (const float*)d_in[0];
    const int*   qweight = (const int*)  d_in[1];
    const float* scales  = (const float*)d_in[2];
    const float* zeros   = (const float*)d_in[3];
    const float* outlier = (const float*)d_in[4];
    const float* grad    = (const float*)d_in[5];
    const float* bias    = (const float*)d_in[6];
    float* out = (float*)d_out;

    u16*   aws  = (u16*)d_ws;                               // 4 MB
    float* part = (float*)((char*)d_ws + (4u << 20));       // 32 MB

    pack_a_kernel<<<(M_TOT * IN_F / 8) / 256, 256, 0, stream>>>(input, aws);
    qlinear_kernel<<<(OUT_F / BN) * KSPLIT, 1024, 0, stream>>>(
        aws, qweight, scales, zeros, outlier, grad, part);
    reduce_kernel<<<(M_TOT * OUT_F / 4) / 256, 256, 0, stream>>>(
        (const fv4*)part, (const fv4*)bias, (fv4*)out);
}

// Round 3
// 213.146 us; speedup vs baseline: 1.1771x; 1.0951x over previous
//
#include <hip/hip_runtime.h>
#include <stdint.h>

#define IN_F   4096
#define OUT_F  4096
#define M_TOT  512
#define KT     (IN_F / 32)      // 128 global 32-wide k-steps
#define BN     64               // weight rows per block (R0 geometry: best measured)
#define BK     64               // K per staging iteration
#define KSPLIT 4
#define KPB    (IN_F / KSPLIT)  // 1024 K per block
#define NITER  (KPB / BK)       // 16 iterations

typedef unsigned short u16;
typedef __bf16 bf16x8 __attribute__((ext_vector_type(8)));
typedef float  f32x4  __attribute__((ext_vector_type(4)));
typedef int    i32x4  __attribute__((ext_vector_type(4)));
typedef float  fv4    __attribute__((ext_vector_type(4)));

__device__ __forceinline__ u16 f2bf(float x) {
    unsigned u = __float_as_uint(x);
    u += 0x7FFFu + ((u >> 16) & 1u);   // round-to-nearest-even
    return (u16)(u >> 16);
}

// ---- pass 0: input fp32 -> bf16, MFMA-A-fragment order in workspace ----
// aws[((mt*KT + kt)*64 + lane)*8 + j] = in[mt*16 + (lane&15)][kt*32 + (lane>>4)*8 + j]
__global__ void pack_a_kernel(const float* __restrict__ in, u16* __restrict__ aws) {
    int t    = blockIdx.x * blockDim.x + threadIdx.x;  // 262144 threads
    int lane = t & 63;
    int kt   = (t >> 6) & (KT - 1);
    int mt   = t >> 13;
    int m = mt * 16 + (lane & 15);
    int k = kt * 32 + ((lane >> 4) << 3);
    const float* src = in + (size_t)m * IN_F + k;
    float4 a0 = *(const float4*)src;
    float4 a1 = *(const float4*)(src + 4);
    union { u16 u[8]; uint4 v; } pk;
    pk.u[0]=f2bf(a0.x); pk.u[1]=f2bf(a0.y); pk.u[2]=f2bf(a0.z); pk.u[3]=f2bf(a0.w);
    pk.u[4]=f2bf(a1.x); pk.u[5]=f2bf(a1.y); pk.u[6]=f2bf(a1.z); pk.u[7]=f2bf(a1.w);
    *(uint4*)(aws + (size_t)t * 8) = pk.v;
}

// ---- main: fused dequant + GEMM; 256 blocks (64 n-tiles x 4 k-quarters), 1024 thr
// BM=512 (weights read exactly once), BN=64.
// R6: the key structural fix — NO vmcnt(0) drain in the main loop.
//   __syncthreads() emits s_waitcnt vmcnt(0) lgkmcnt(0); that drained the entire
//   VMEM queue every iteration, collapsing any prefetch depth to <=1 body and
//   idling the memory system between barrier-synced bursts (R0-R5 all capped at
//   1.4-1.5 TB/s effective). Replaced with: s_waitcnt lgkmcnt(0) (LDS visibility,
//   the only thing the barrier must order — staging prefetch lands in private
//   VGPRs) + raw s_barrier. Staging loads now stay in flight ACROSS barriers
//   (T4, m218: +38-73%).
// VMEM issue order per iteration: A-frag loads FIRST, then ld(it+2) staging.
//   MFMA's A-wait is then vmcnt(3) — leaving the fresh staging loads in flight —
//   instead of vmcnt(0).
__global__ __launch_bounds__(1024, 4) void qlinear_kernel(
    const u16*   __restrict__ aws,
    const int*   __restrict__ qw,
    const float* __restrict__ scales,
    const float* __restrict__ zeros,
    const float* __restrict__ outlier,
    const float* __restrict__ grad,
    float*       __restrict__ part)           // [KSPLIT][512][4096]
{
    // buffer = 8 frags (ks*4+nf) x 64 lanes x 8 bf16 = 8 KB; double-buffered 16 KB
    __shared__ __align__(16) u16 Bsh[2][8 * 64 * 8];

    const int tid  = threadIdx.x;
    const int lane = tid & 63;
    const int wv   = tid >> 6;                // 0..15, m-stripe [wv*32, +32)

    const int nblk = blockIdx.x >> 2;
    const int kq   = blockIdx.x & 3;
    const int n0   = nblk * BN;
    const int k0   = kq * KPB;

    // ---- staging role: thread covers weight row (n0+srow), 4-wide k-chunk ----
    const int srow = tid >> 4;                // 0..63
    const int schk = tid & 15;                // k_local = schk*4 (0..60)
    const int orow = n0 + srow;
    const float sr = scales[orow];
    const float c0 = -zeros[orow] * sr;       // w = q*s + (o*g - z*s)
    const size_t sg = (size_t)orow * IN_F + k0 + schk * 4;
    // B-frag coords (layout verified R1/R3): frag = ks*4+nf, lane = (n&15)|(quad<<4)
    const int sks   = schk >> 3;              // k_local>>5
    const int squad = (schk >> 1) & 3;        // (k_local>>3)&3
    const int j0    = (schk & 1) * 4;         // k_local&7 base
    const int snf   = srow >> 4;
    const int slane = (srow & 15) | (squad << 4);
    const int doff  = ((sks * 4 + snf) * 64 + slane) * 8 + j0;

    i32x4 qb[2]; fv4 ob[2], gb[2];
    auto ld = [&](int it) {
        int s = it & 1;
        size_t off = sg + (size_t)it * BK;
        qb[s] = __builtin_nontemporal_load((const i32x4*)(qw      + off));
        ob[s] = __builtin_nontemporal_load((const fv4*)  (outlier + off));
        gb[s] = __builtin_nontemporal_load((const fv4*)  (grad    + off));
    };
    auto st = [&](int it) {
        int s = it & 1;
        union { u16 u[4]; uint2 v; } pk;
        pk.u[0] = f2bf(fmaf((float)qb[s].x, sr, fmaf(ob[s].x, gb[s].x, c0)));
        pk.u[1] = f2bf(fmaf((float)qb[s].y, sr, fmaf(ob[s].y, gb[s].y, c0)));
        pk.u[2] = f2bf(fmaf((float)qb[s].z, sr, fmaf(ob[s].z, gb[s].z, c0)));
        pk.u[3] = f2bf(fmaf((float)qb[s].w, sr, fmaf(ob[s].w, gb[s].w, c0)));
        *(uint2*)(&Bsh[it & 1][doff]) = pk.v;
    };

    // A fragment base: frag (mf, d) at abase + (mf*KT + d)*512, d = global 32-k step
    const u16* abase = aws + ((size_t)(wv * 2) * KT + kq * (KPB / 32)) * 512
                           + (size_t)lane * 8;

    f32x4 acc[2][4] = {};

    ld(0);
    ld(1);
    st(0);                                    // waits only its own loads (vmcnt(3))
    asm volatile("s_waitcnt lgkmcnt(0)" ::: "memory");
    __builtin_amdgcn_s_barrier();

    for (int it = 0; it < NITER; ++it) {
        // A loads first in VMEM order: the MFMA wait becomes vmcnt(3), leaving
        // the staging loads (issued below) in flight through the barrier.
        bf16x8 af[2][2];
        #pragma unroll
        for (int ks = 0; ks < 2; ++ks)
            #pragma unroll
            for (int mf = 0; mf < 2; ++mf)
                af[ks][mf] = *(const bf16x8*)(abase + ((size_t)mf * KT + it * 2 + ks) * 512);

        // staging loads for it+2 — newest in the queue, never waited this iter
        if (it + 2 < NITER) ld(it + 2);

        const u16* bb = &Bsh[it & 1][0];
        #pragma unroll
        for (int ks = 0; ks < 2; ++ks) {
            bf16x8 bfr[4];
            #pragma unroll
            for (int nf = 0; nf < 4; ++nf)
                bfr[nf] = *(const bf16x8*)(bb + (((ks * 4 + nf) * 64) + lane) * 8);
            #pragma unroll
            for (int mf = 0; mf < 2; ++mf)
                #pragma unroll
                for (int nf = 0; nf < 4; ++nf)
                    acc[mf][nf] = __builtin_amdgcn_mfma_f32_16x16x32_bf16(
                        af[ks][mf], bfr[nf], acc[mf][nf], 0, 0, 0);
        }

        // dequant + LDS-write for it+1 (its loads aged >=1 full body; already
        // forced complete by the A-load vmcnt wait above — no extra stall)
        if (it + 1 < NITER) st(it + 1);

        // barrier WITHOUT vmcnt drain: only LDS ops must be visible
        asm volatile("s_waitcnt lgkmcnt(0)" ::: "memory");
        __builtin_amdgcn_s_barrier();
    }

    // ---- epilogue: fp32 partials, non-temporal (write-once-read-once) ----
    float* pout = part + (size_t)kq * (M_TOT * OUT_F);
    const int cm0 = wv * 32 + ((lane >> 4) << 2);
    const int cn  = n0 + (lane & 15);
    #pragma unroll
    for (int mf = 0; mf < 2; ++mf)
        #pragma unroll
        for (int nf = 0; nf < 4; ++nf)
            #pragma unroll
            for (int r = 0; r < 4; ++r)
                __builtin_nontemporal_store(
                    acc[mf][nf][r],
                    pout + (size_t)(cm0 + mf * 16 + r) * OUT_F + cn + nf * 16);
}

// ---- reduce: out = bias + sum_k partial[k] ----
__global__ void reduce_kernel(const fv4* __restrict__ part,
                              const fv4* __restrict__ bias,
                              fv4* __restrict__ out) {
    int idx = blockIdx.x * blockDim.x + threadIdx.x;   // 524288
    fv4 s = bias[idx & (OUT_F / 4 - 1)];
    const int STRIDE = M_TOT * OUT_F / 4;
    #pragma unroll
    for (int k = 0; k < KSPLIT; ++k) {
        fv4 p = __builtin_nontemporal_load(part + (size_t)k * STRIDE + idx);
        s += p;
    }
    out[idx] = s;
}

extern "C" void kernel_launch(void* const* d_in, const int* in_sizes, int n_in,
                              void* d_out, int out_size, void* d_ws, size_t ws_size,
                              hipStream_t stream) {
    const float* input   = (const float*)d_in[0];
    const int*   qweight = (const int*)  d_in[1];
    const float* scales  = (const float*)d_in[2];
    const float* zeros   = (const float*)d_in[3];
    const float* outlier = (const float*)d_in[4];
    const float* grad    = (const float*)d_in[5];
    const float* bias    = (const float*)d_in[6];
    float* out = (float*)d_out;

    u16*   aws  = (u16*)d_ws;                               // 4 MB
    float* part = (float*)((char*)d_ws + (4u << 20));       // 32 MB

    pack_a_kernel<<<(M_TOT * IN_F / 8) / 256, 256, 0, stream>>>(input, aws);
    qlinear_kernel<<<(OUT_F / BN) * KSPLIT, 1024, 0, stream>>>(
        aws, qweight, scales, zeros, outlier, grad, part);
    reduce_kernel<<<(M_TOT * OUT_F / 4) / 256, 256, 0, stream>>>(
        (const fv4*)part, (const fv4*)bias, (fv4*)out);
}